// Round 1
// baseline (3729.356 us; speedup 1.0000x reference)
//
#include <hip/hip_runtime.h>
#include <cmath>

#define NN 50000
#define NE 800000
#define INF_ 128
#define NR 64
#define OF 128

// ---- sortable-uint encoding for float atomicMax ----
__device__ __forceinline__ unsigned enc_f(float f) {
  unsigned u = __float_as_uint(f);
  return (u & 0x80000000u) ? ~u : (u | 0x80000000u);
}
__device__ __forceinline__ float dec_f(unsigned u) {
  unsigned b = (u & 0x80000000u) ? (u & 0x7fffffffu) : ~u;
  return __uint_as_float(b);
}

// init m_enc = enc(-inf), s = 0
__global__ void k_init(unsigned* m_enc, float* s) {
  int i = blockIdx.x * blockDim.x + threadIdx.x;
  if (i < NN) { m_enc[i] = 0x007FFFFFu; s[i] = 0.f; }
}

// q3[d] = sum_j W[(256+d),j] * a[j]   (W3 @ a, 64 values)
__global__ void k_q3(const float* __restrict__ W, const float* __restrict__ a,
                     float* __restrict__ q3) {
  int t = threadIdx.x;
  if (t < NR) {
    const float* row = W + (size_t)(2 * INF_ + t) * OF;
    float acc = 0.f;
    for (int j = 0; j < OF; ++j) acc = fmaf(row[j], a[j], acc);
    q3[t] = acc;
  }
}

// per-node precompute: xW1 = x@W1, xW2 = x@W2, p1 = xW1@a, p2 = xW2@a
// 8 nodes per block, 128 threads (thread = output column)
__global__ void k_node_pre(const float* __restrict__ x, const float* __restrict__ W,
                           const float* __restrict__ a,
                           float* __restrict__ xW1, float* __restrict__ xW2,
                           float* __restrict__ p1, float* __restrict__ p2) {
  __shared__ float xs[8][INF_];
  __shared__ float red[2][2][8];
  int nb = blockIdx.x * 8;
  int o = threadIdx.x;  // 0..127
  for (int t = 0; t < 8; ++t) xs[t][o] = x[(size_t)(nb + t) * INF_ + o];
  __syncthreads();
  float acc1[8] = {0.f, 0.f, 0.f, 0.f, 0.f, 0.f, 0.f, 0.f};
  float acc2[8] = {0.f, 0.f, 0.f, 0.f, 0.f, 0.f, 0.f, 0.f};
  for (int k = 0; k < INF_; ++k) {
    float w1 = W[(size_t)k * OF + o];
    float w2 = W[(size_t)(INF_ + k) * OF + o];
#pragma unroll
    for (int t = 0; t < 8; ++t) {
      acc1[t] = fmaf(xs[t][k], w1, acc1[t]);
      acc2[t] = fmaf(xs[t][k], w2, acc2[t]);
    }
  }
  float av = a[o];
  int wv = o >> 6, ln = o & 63;
#pragma unroll
  for (int t = 0; t < 8; ++t) {
    xW1[(size_t)(nb + t) * OF + o] = acc1[t];
    xW2[(size_t)(nb + t) * OF + o] = acc2[t];
    float v1 = acc1[t] * av, v2 = acc2[t] * av;
    for (int off = 32; off > 0; off >>= 1) {
      v1 += __shfl_down(v1, off, 64);
      v2 += __shfl_down(v2, off, 64);
    }
    if (ln == 0) { red[0][wv][t] = v1; red[1][wv][t] = v2; }
  }
  __syncthreads();
  if (o < 8) {
    p1[nb + o] = red[0][0][o] + red[0][1][o];
    p2[nb + o] = red[1][0][o] + red[1][1][o];
  }
}

// per-edge logit: alpha[e] = leaky_relu(p1[src] + p2[dst] + ete[e]·q3); atomicMax m
// 16 lanes per edge (float4 each), 16 edges per 256-thread block
__global__ void k_alpha(const int* __restrict__ ei, const float* __restrict__ ete,
                        const float* __restrict__ q3,
                        const float* __restrict__ p1, const float* __restrict__ p2,
                        float* __restrict__ alpha, unsigned* __restrict__ m_enc) {
  int l = threadIdx.x & 15;
  int e = blockIdx.x * 16 + (threadIdx.x >> 4);
  if (e >= NE) return;
  float4 t4 = ((const float4*)(ete + (size_t)e * NR))[l];
  float4 q4 = ((const float4*)q3)[l];
  float d = t4.x * q4.x + t4.y * q4.y + t4.z * q4.z + t4.w * q4.w;
  d += __shfl_xor(d, 8, 16);
  d += __shfl_xor(d, 4, 16);
  d += __shfl_xor(d, 2, 16);
  d += __shfl_xor(d, 1, 16);
  if (l == 0) {
    int src = ei[e], dst = ei[NE + e];
    float v = p1[src] + p2[dst] + d;
    v = v > 0.f ? v : 0.2f * v;
    alpha[e] = v;
    atomicMax(m_enc + src, enc_f(v));
  }
}

// ev = exp(alpha - m[src]); s[src] += ev  (in-place overwrite of alpha buffer)
__global__ void k_exp(const int* __restrict__ ei, const unsigned* __restrict__ m_enc,
                      float* __restrict__ ev, float* __restrict__ s) {
  int e = blockIdx.x * blockDim.x + threadIdx.x;
  if (e < NE) {
    int src = ei[e];
    float v = __expf(ev[e] - dec_f(m_enc[src]));
    ev[e] = v;
    atomicAdd(s + src, v);
  }
}

// aggregation: g[src] += w*ete[e] (64-wide), out[src] += w*xW2[dst] (128-wide)
__global__ void k_agg(const int* __restrict__ ei, const float* __restrict__ ete,
                      const float* __restrict__ xW2, const float* __restrict__ ev,
                      const float* __restrict__ s,
                      float* __restrict__ g, float* __restrict__ out) {
  int l = threadIdx.x & 15;
  int e = blockIdx.x * 16 + (threadIdx.x >> 4);
  if (e >= NE) return;
  int src = ei[e];
  int dst = ei[NE + e];
  float w = ev[e] / (s[src] + 1e-16f);
  float4 t4 = ((const float4*)(ete + (size_t)e * NR))[l];
  float* gb = g + (size_t)src * NR + l * 4;
  atomicAdd(gb + 0, w * t4.x);
  atomicAdd(gb + 1, w * t4.y);
  atomicAdd(gb + 2, w * t4.z);
  atomicAdd(gb + 3, w * t4.w);
  const float4* xr = (const float4*)(xW2 + (size_t)dst * OF);
  float4 v0 = xr[l * 2], v1 = xr[l * 2 + 1];
  float* ob = out + (size_t)src * OF + l * 8;
  atomicAdd(ob + 0, w * v0.x);
  atomicAdd(ob + 1, w * v0.y);
  atomicAdd(ob + 2, w * v0.z);
  atomicAdd(ob + 3, w * v0.w);
  atomicAdd(ob + 4, w * v1.x);
  atomicAdd(ob + 5, w * v1.y);
  atomicAdd(ob + 6, w * v1.z);
  atomicAdd(ob + 7, w * v1.w);
}

// finalize: out = elu( (s/(s+1e-16))*xW1 + out + g@W3 ), 8 nodes/block
__global__ void k_final(const float* __restrict__ xW1, const float* __restrict__ g,
                        const float* __restrict__ s, const float* __restrict__ W,
                        float* __restrict__ out) {
  __shared__ float gs[8 * NR];
  int nb = blockIdx.x * 8;
  int o = threadIdx.x;  // 0..127
  for (int i = o; i < 8 * NR; i += 128) gs[i] = g[(size_t)nb * NR + i];
  __syncthreads();
  float acc[8] = {0.f, 0.f, 0.f, 0.f, 0.f, 0.f, 0.f, 0.f};
  for (int d = 0; d < NR; ++d) {
    float w3 = W[(size_t)(2 * INF_ + d) * OF + o];
#pragma unroll
    for (int t = 0; t < 8; ++t) acc[t] = fmaf(gs[t * NR + d], w3, acc[t]);
  }
#pragma unroll
  for (int t = 0; t < 8; ++t) {
    int n = nb + t;
    float sv = s[n];
    float sa = sv > 0.f ? sv / (sv + 1e-16f) : 0.f;
    float v = sa * xW1[(size_t)n * OF + o] + out[(size_t)n * OF + o] + acc[t];
    out[(size_t)n * OF + o] = v > 0.f ? v : expm1f(v);
  }
}

extern "C" void kernel_launch(void* const* d_in, const int* in_sizes, int n_in,
                              void* d_out, int out_size, void* d_ws, size_t ws_size,
                              hipStream_t stream) {
  const int* ei = (const int*)d_in[0];
  const float* x = (const float*)d_in[1];
  const float* ete = (const float*)d_in[2];
  const float* W = (const float*)d_in[3];
  const float* a = (const float*)d_in[4];
  float* out = (float*)d_out;

  float* ws = (float*)d_ws;
  float* xW1 = ws;                                  // N*128
  float* xW2 = xW1 + (size_t)NN * OF;               // N*128
  float* p1 = xW2 + (size_t)NN * OF;                // N
  float* p2 = p1 + NN;                              // N
  float* q3 = p2 + NN;                              // 64
  unsigned* m_enc = (unsigned*)(q3 + NR);           // N
  float* s = (float*)(m_enc + NN);                  // N
  float* ev = s + NN;                               // E
  float* g = ev + NE;                               // N*64
  // total ~17.0M floats = 68 MB

  hipMemsetAsync(g, 0, (size_t)NN * NR * sizeof(float), stream);
  hipMemsetAsync(out, 0, (size_t)NN * OF * sizeof(float), stream);
  k_init<<<(NN + 255) / 256, 256, 0, stream>>>(m_enc, s);
  k_q3<<<1, 64, 0, stream>>>(W, a, q3);
  k_node_pre<<<NN / 8, 128, 0, stream>>>(x, W, a, xW1, xW2, p1, p2);
  k_alpha<<<NE / 16, 256, 0, stream>>>(ei, ete, q3, p1, p2, ev, m_enc);
  k_exp<<<NE / 256, 256, 0, stream>>>(ei, m_enc, ev, s);
  k_agg<<<NE / 16, 256, 0, stream>>>(ei, ete, xW2, ev, s, g, out);
  k_final<<<NN / 8, 128, 0, stream>>>(xW1, g, s, W, out);
}

// Round 2
// 515.080 us; speedup vs baseline: 7.2403x; 7.2403x over previous
//
#include <hip/hip_runtime.h>
#include <cmath>

#define NN 50000
#define NE 800000
#define INF_ 128
#define NR 64
#define OF 128
#define SCAN_T 1024

// ---- sortable-uint encoding for float atomicMax ----
__device__ __forceinline__ unsigned enc_f(float f) {
  unsigned u = __float_as_uint(f);
  return (u & 0x80000000u) ? ~u : (u | 0x80000000u);
}
__device__ __forceinline__ float dec_f(unsigned u) {
  unsigned b = (u & 0x80000000u) ? (u & 0x7fffffffu) : ~u;
  return __uint_as_float(b);
}

// init m_enc = enc(-inf), s = 0
__global__ void k_init(unsigned* m_enc, float* s) {
  int i = blockIdx.x * blockDim.x + threadIdx.x;
  if (i < NN) { m_enc[i] = 0x007FFFFFu; s[i] = 0.f; }
}

// q3[d] = sum_j W[(256+d),j] * a[j]
__global__ void k_q3(const float* __restrict__ W, const float* __restrict__ a,
                     float* __restrict__ q3) {
  int t = threadIdx.x;
  if (t < NR) {
    const float* row = W + (size_t)(2 * INF_ + t) * OF;
    float acc = 0.f;
    for (int j = 0; j < OF; ++j) acc = fmaf(row[j], a[j], acc);
    q3[t] = acc;
  }
}

// per-node precompute: xW1 = x@W1, xW2 = x@W2, p1 = xW1@a, p2 = xW2@a
__global__ void k_node_pre(const float* __restrict__ x, const float* __restrict__ W,
                           const float* __restrict__ a,
                           float* __restrict__ xW1, float* __restrict__ xW2,
                           float* __restrict__ p1, float* __restrict__ p2) {
  __shared__ float xs[8][INF_];
  __shared__ float red[2][2][8];
  int nb = blockIdx.x * 8;
  int o = threadIdx.x;  // 0..127
  for (int t = 0; t < 8; ++t) xs[t][o] = x[(size_t)(nb + t) * INF_ + o];
  __syncthreads();
  float acc1[8] = {0.f, 0.f, 0.f, 0.f, 0.f, 0.f, 0.f, 0.f};
  float acc2[8] = {0.f, 0.f, 0.f, 0.f, 0.f, 0.f, 0.f, 0.f};
  for (int k = 0; k < INF_; ++k) {
    float w1 = W[(size_t)k * OF + o];
    float w2 = W[(size_t)(INF_ + k) * OF + o];
#pragma unroll
    for (int t = 0; t < 8; ++t) {
      acc1[t] = fmaf(xs[t][k], w1, acc1[t]);
      acc2[t] = fmaf(xs[t][k], w2, acc2[t]);
    }
  }
  float av = a[o];
  int wv = o >> 6, ln = o & 63;
#pragma unroll
  for (int t = 0; t < 8; ++t) {
    xW1[(size_t)(nb + t) * OF + o] = acc1[t];
    xW2[(size_t)(nb + t) * OF + o] = acc2[t];
    float v1 = acc1[t] * av, v2 = acc2[t] * av;
    for (int off = 32; off > 0; off >>= 1) {
      v1 += __shfl_down(v1, off, 64);
      v2 += __shfl_down(v2, off, 64);
    }
    if (ln == 0) { red[0][wv][t] = v1; red[1][wv][t] = v2; }
  }
  __syncthreads();
  if (o < 8) {
    p1[nb + o] = red[0][0][o] + red[0][1][o];
    p2[nb + o] = red[1][0][o] + red[1][1][o];
  }
}

// per-edge logit + histogram: alpha[e] = leaky_relu(p1[src]+p2[dst]+ete[e]·q3)
__global__ void k_alpha(const int* __restrict__ ei, const float* __restrict__ ete,
                        const float* __restrict__ q3,
                        const float* __restrict__ p1, const float* __restrict__ p2,
                        float* __restrict__ alpha, unsigned* __restrict__ m_enc,
                        int* __restrict__ cnt) {
  int l = threadIdx.x & 15;
  int e = blockIdx.x * 16 + (threadIdx.x >> 4);
  if (e >= NE) return;
  float4 t4 = ((const float4*)(ete + (size_t)e * NR))[l];
  float4 q4 = ((const float4*)q3)[l];
  float d = t4.x * q4.x + t4.y * q4.y + t4.z * q4.z + t4.w * q4.w;
  d += __shfl_xor(d, 8, 16);
  d += __shfl_xor(d, 4, 16);
  d += __shfl_xor(d, 2, 16);
  d += __shfl_xor(d, 1, 16);
  if (l == 0) {
    int src = ei[e], dst = ei[NE + e];
    float v = p1[src] + p2[dst] + d;
    v = v > 0.f ? v : 0.2f * v;
    alpha[e] = v;
    atomicMax(m_enc + src, enc_f(v));
    atomicAdd(cnt + src, 1);
  }
}

// single-block exclusive scan over cnt -> roff (+cur copy); roff[NN]=NE
__global__ void k_scan(const int* __restrict__ cnt, int* __restrict__ roff,
                       int* __restrict__ cur) {
  __shared__ int part[SCAN_T];
  int t = threadIdx.x;
  const int chunk = (NN + SCAN_T - 1) / SCAN_T;  // 49
  int beg = t * chunk;
  int end = beg + chunk < NN ? beg + chunk : NN;
  int sum = 0;
  for (int i = beg; i < end; ++i) sum += cnt[i];
  part[t] = sum;
  __syncthreads();
  for (int off = 1; off < SCAN_T; off <<= 1) {
    int v = (t >= off) ? part[t - off] : 0;
    __syncthreads();
    part[t] += v;
    __syncthreads();
  }
  int run = (t == 0) ? 0 : part[t - 1];
  for (int i = beg; i < end; ++i) {
    roff[i] = run;
    cur[i] = run;
    run += cnt[i];
  }
  if (t == SCAN_T - 1) roff[NN] = NE;
}

// ev = exp(alpha - m[src]); s[src] += ev; scatter (e,dst) into CSR slot
__global__ void k_exp(const int* __restrict__ ei, const unsigned* __restrict__ m_enc,
                      float* __restrict__ ev, float* __restrict__ s,
                      int* __restrict__ cur, int2* __restrict__ es) {
  int e = blockIdx.x * blockDim.x + threadIdx.x;
  if (e < NE) {
    int src = ei[e];
    float v = __expf(ev[e] - dec_f(m_enc[src]));
    ev[e] = v;
    atomicAdd(s + src, v);
    int pos = atomicAdd(cur + src, 1);
    es[pos] = make_int2(e, ei[NE + e]);
  }
}

// per-node gather: one wave per node, register accumulation, plain stores
__global__ void k_gather(const int2* __restrict__ es, const int* __restrict__ roff,
                         const float* __restrict__ ete, const float* __restrict__ xW2,
                         const float* __restrict__ ev, const float* __restrict__ s,
                         float* __restrict__ g, float* __restrict__ out) {
  int n = blockIdx.x * 4 + (threadIdx.x >> 6);
  int l = threadIdx.x & 63;
  if (n >= NN) return;
  int beg = roff[n], end = roff[n + 1];
  float inv = 1.f / (s[n] + 1e-16f);
  float gacc = 0.f, o0 = 0.f, o1 = 0.f;
  for (int j = beg; j < end; ++j) {
    int2 ed = es[j];
    float w = ev[ed.x] * inv;
    gacc = fmaf(w, ete[(size_t)ed.x * NR + l], gacc);
    o0 = fmaf(w, xW2[(size_t)ed.y * OF + l], o0);
    o1 = fmaf(w, xW2[(size_t)ed.y * OF + 64 + l], o1);
  }
  g[(size_t)n * NR + l] = gacc;
  out[(size_t)n * OF + l] = o0;
  out[(size_t)n * OF + 64 + l] = o1;
}

// finalize: out = elu( (s/(s+1e-16))*xW1 + out + g@W3 ), 8 nodes/block
__global__ void k_final(const float* __restrict__ xW1, const float* __restrict__ g,
                        const float* __restrict__ s, const float* __restrict__ W,
                        float* __restrict__ out) {
  __shared__ float gs[8 * NR];
  int nb = blockIdx.x * 8;
  int o = threadIdx.x;  // 0..127
  for (int i = o; i < 8 * NR; i += 128) gs[i] = g[(size_t)nb * NR + i];
  __syncthreads();
  float acc[8] = {0.f, 0.f, 0.f, 0.f, 0.f, 0.f, 0.f, 0.f};
  for (int d = 0; d < NR; ++d) {
    float w3 = W[(size_t)(2 * INF_ + d) * OF + o];
#pragma unroll
    for (int t = 0; t < 8; ++t) acc[t] = fmaf(gs[t * NR + d], w3, acc[t]);
  }
#pragma unroll
  for (int t = 0; t < 8; ++t) {
    int n = nb + t;
    float sv = s[n];
    float sa = sv > 0.f ? sv / (sv + 1e-16f) : 0.f;
    float v = sa * xW1[(size_t)n * OF + o] + out[(size_t)n * OF + o] + acc[t];
    out[(size_t)n * OF + o] = v > 0.f ? v : expm1f(v);
  }
}

extern "C" void kernel_launch(void* const* d_in, const int* in_sizes, int n_in,
                              void* d_out, int out_size, void* d_ws, size_t ws_size,
                              hipStream_t stream) {
  const int* ei = (const int*)d_in[0];
  const float* x = (const float*)d_in[1];
  const float* ete = (const float*)d_in[2];
  const float* W = (const float*)d_in[3];
  const float* a = (const float*)d_in[4];
  float* out = (float*)d_out;

  float* ws = (float*)d_ws;
  float* xW1 = ws;                                  // N*128
  float* xW2 = xW1 + (size_t)NN * OF;               // N*128
  float* p1 = xW2 + (size_t)NN * OF;                // N
  float* p2 = p1 + NN;                              // N
  float* q3 = p2 + NN;                              // 64
  unsigned* m_enc = (unsigned*)(q3 + NR);           // N
  float* s = (float*)(m_enc + NN);                  // N
  float* ev = s + NN;                               // E
  float* g = ev + NE;                               // N*64
  int* cnt = (int*)(g + (size_t)NN * NR);           // N
  int* roff = cnt + NN;                             // N+1
  int* cur = roff + NN + 1;                         // N
  int2* es = (int2*)(cur + NN + 1);                 // E int2
  // total ~20M * 4B = 80 MB

  hipMemsetAsync(cnt, 0, NN * sizeof(int), stream);
  k_init<<<(NN + 255) / 256, 256, 0, stream>>>(m_enc, s);
  k_q3<<<1, 64, 0, stream>>>(W, a, q3);
  k_node_pre<<<NN / 8, 128, 0, stream>>>(x, W, a, xW1, xW2, p1, p2);
  k_alpha<<<NE / 16, 256, 0, stream>>>(ei, ete, q3, p1, p2, ev, m_enc, cnt);
  k_scan<<<1, SCAN_T, 0, stream>>>(cnt, roff, cur);
  k_exp<<<NE / 256, 256, 0, stream>>>(ei, m_enc, ev, s, cur, es);
  k_gather<<<(NN + 3) / 4, 256, 0, stream>>>(es, roff, ete, xW2, ev, s, g, out);
  k_final<<<NN / 8, 128, 0, stream>>>(xW1, g, s, W, out);
}

// Round 3
// 448.738 us; speedup vs baseline: 8.3108x; 1.1478x over previous
//
#include <hip/hip_runtime.h>
#include <cmath>

#define NN 50000
#define NE 800000
#define INF_ 128
#define NR 64
#define OF 128
#define SCAN_T 1024

// q3[d] = sum_j W[(256+d),j] * a[j]
__global__ void k_q3(const float* __restrict__ W, const float* __restrict__ a,
                     float* __restrict__ q3) {
  int t = threadIdx.x;
  if (t < NR) {
    const float* row = W + (size_t)(2 * INF_ + t) * OF;
    float acc = 0.f;
    for (int j = 0; j < OF; ++j) acc = fmaf(row[j], a[j], acc);
    q3[t] = acc;
  }
}

// per-node precompute: xW1 = x@W1, xW2 = x@W2, p1 = xW1@a, p2 = xW2@a
__global__ void k_node_pre(const float* __restrict__ x, const float* __restrict__ W,
                           const float* __restrict__ a,
                           float* __restrict__ xW1, float* __restrict__ xW2,
                           float* __restrict__ p1, float* __restrict__ p2) {
  __shared__ float xs[8][INF_];
  __shared__ float red[2][2][8];
  int nb = blockIdx.x * 8;
  int o = threadIdx.x;  // 0..127
  for (int t = 0; t < 8; ++t) xs[t][o] = x[(size_t)(nb + t) * INF_ + o];
  __syncthreads();
  float acc1[8] = {0.f, 0.f, 0.f, 0.f, 0.f, 0.f, 0.f, 0.f};
  float acc2[8] = {0.f, 0.f, 0.f, 0.f, 0.f, 0.f, 0.f, 0.f};
  for (int k = 0; k < INF_; ++k) {
    float w1 = W[(size_t)k * OF + o];
    float w2 = W[(size_t)(INF_ + k) * OF + o];
#pragma unroll
    for (int t = 0; t < 8; ++t) {
      acc1[t] = fmaf(xs[t][k], w1, acc1[t]);
      acc2[t] = fmaf(xs[t][k], w2, acc2[t]);
    }
  }
  float av = a[o];
  int wv = o >> 6, ln = o & 63;
#pragma unroll
  for (int t = 0; t < 8; ++t) {
    xW1[(size_t)(nb + t) * OF + o] = acc1[t];
    xW2[(size_t)(nb + t) * OF + o] = acc2[t];
    float v1 = acc1[t] * av, v2 = acc2[t] * av;
    for (int off = 32; off > 0; off >>= 1) {
      v1 += __shfl_down(v1, off, 64);
      v2 += __shfl_down(v2, off, 64);
    }
    if (ln == 0) { red[0][wv][t] = v1; red[1][wv][t] = v2; }
  }
  __syncthreads();
  if (o < 8) {
    p1[nb + o] = red[0][0][o] + red[0][1][o];
    p2[nb + o] = red[1][0][o] + red[1][1][o];
  }
}

// fused edge pass: ev[e] = exp(leaky_relu(p1[src]+p2[dst]+ete[e]·q3));
// s[src] += ev; cnt[src]++.   (no segment-max: |logit| << 88, exp is safe)
__global__ void k_edge(const int* __restrict__ ei, const float* __restrict__ ete,
                       const float* __restrict__ q3,
                       const float* __restrict__ p1, const float* __restrict__ p2,
                       float* __restrict__ ev, float* __restrict__ s,
                       int* __restrict__ cnt) {
  int l = threadIdx.x & 15;
  int e = blockIdx.x * 16 + (threadIdx.x >> 4);
  if (e >= NE) return;
  float4 t4 = ((const float4*)(ete + (size_t)e * NR))[l];
  float4 q4 = ((const float4*)q3)[l];
  float d = t4.x * q4.x + t4.y * q4.y + t4.z * q4.z + t4.w * q4.w;
  d += __shfl_xor(d, 8, 16);
  d += __shfl_xor(d, 4, 16);
  d += __shfl_xor(d, 2, 16);
  d += __shfl_xor(d, 1, 16);
  if (l == 0) {
    int src = ei[e], dst = ei[NE + e];
    float v = p1[src] + p2[dst] + d;
    v = v > 0.f ? v : 0.2f * v;
    float xv = __expf(v);
    ev[e] = xv;
    atomicAdd(s + src, xv);
    atomicAdd(cnt + src, 1);
  }
}

// single-block exclusive scan over cnt -> roff (+cur copy); roff[NN]=NE
__global__ void k_scan(const int* __restrict__ cnt, int* __restrict__ roff,
                       int* __restrict__ cur) {
  __shared__ int part[SCAN_T];
  int t = threadIdx.x;
  const int chunk = (NN + SCAN_T - 1) / SCAN_T;  // 49
  int beg = t * chunk;
  int end = beg + chunk < NN ? beg + chunk : NN;
  int sum = 0;
  for (int i = beg; i < end; ++i) sum += cnt[i];
  part[t] = sum;
  __syncthreads();
  for (int off = 1; off < SCAN_T; off <<= 1) {
    int v = (t >= off) ? part[t - off] : 0;
    __syncthreads();
    part[t] += v;
    __syncthreads();
  }
  int run = (t == 0) ? 0 : part[t - 1];
  for (int i = beg; i < end; ++i) {
    roff[i] = run;
    cur[i] = run;
    run += cnt[i];
  }
  if (t == SCAN_T - 1) roff[NN] = NE;
}

// scatter edges into CSR slots; w = ev/(s+eps) computed here (s is final)
__global__ void k_scatter(const int* __restrict__ ei, const float* __restrict__ ev,
                          const float* __restrict__ s, int* __restrict__ cur,
                          int2* __restrict__ es, float* __restrict__ wcsr) {
  int e = blockIdx.x * blockDim.x + threadIdx.x;
  if (e < NE) {
    int src = ei[e];
    int pos = atomicAdd(cur + src, 1);
    es[pos] = make_int2(e, ei[NE + e]);
    wcsr[pos] = ev[e] * (1.f / (s[src] + 1e-16f));
  }
}

// per-node gather: one wave per node. Metadata bulk-loaded coalesced, then
// broadcast via wave-uniform shfl; 4 edges of independent loads per step.
__global__ void k_gather(const int2* __restrict__ es, const float* __restrict__ wcsr,
                         const int* __restrict__ roff,
                         const float* __restrict__ ete, const float* __restrict__ xW2,
                         float* __restrict__ g, float* __restrict__ out) {
  int n = blockIdx.x * 4 + (threadIdx.x >> 6);
  int l = threadIdx.x & 63;
  if (n >= NN) return;
  int beg = roff[n], end = roff[n + 1];
  float gacc = 0.f, o0 = 0.f, o1 = 0.f;
  for (int jb = beg; jb < end; jb += 64) {
    int m = end - jb;
    if (m > 64) m = 64;
    int2 ed = make_int2(0, 0);
    float wv = 0.f;
    if (jb + l < end) { ed = es[jb + l]; wv = wcsr[jb + l]; }
    for (int jj = 0; jj < m; jj += 4) {
#pragma unroll
      for (int q = 0; q < 4; ++q) {
        // jj+q <= 63 always; padded lanes carry w=0 and safe (0,0) indices
        int e_q = __shfl(ed.x, jj + q, 64);
        int d_q = __shfl(ed.y, jj + q, 64);
        float w_q = __shfl(wv, jj + q, 64);
        float tv = ete[(size_t)e_q * NR + l];
        float2 xv = *(const float2*)(xW2 + (size_t)d_q * OF + 2 * l);
        gacc = fmaf(w_q, tv, gacc);
        o0 = fmaf(w_q, xv.x, o0);
        o1 = fmaf(w_q, xv.y, o1);
      }
    }
  }
  g[(size_t)n * NR + l] = gacc;
  *(float2*)(out + (size_t)n * OF + 2 * l) = make_float2(o0, o1);
}

// finalize: out = elu( (s/(s+1e-16))*xW1 + out + g@W3 ), 8 nodes/block
__global__ void k_final(const float* __restrict__ xW1, const float* __restrict__ g,
                        const float* __restrict__ s, const float* __restrict__ W,
                        float* __restrict__ out) {
  __shared__ float gs[8 * NR];
  int nb = blockIdx.x * 8;
  int o = threadIdx.x;  // 0..127
  for (int i = o; i < 8 * NR; i += 128) gs[i] = g[(size_t)nb * NR + i];
  __syncthreads();
  float acc[8] = {0.f, 0.f, 0.f, 0.f, 0.f, 0.f, 0.f, 0.f};
  for (int d = 0; d < NR; ++d) {
    float w3 = W[(size_t)(2 * INF_ + d) * OF + o];
#pragma unroll
    for (int t = 0; t < 8; ++t) acc[t] = fmaf(gs[t * NR + d], w3, acc[t]);
  }
#pragma unroll
  for (int t = 0; t < 8; ++t) {
    int n = nb + t;
    float sv = s[n];
    float sa = sv > 0.f ? sv / (sv + 1e-16f) : 0.f;
    float v = sa * xW1[(size_t)n * OF + o] + out[(size_t)n * OF + o] + acc[t];
    out[(size_t)n * OF + o] = v > 0.f ? v : expm1f(v);
  }
}

extern "C" void kernel_launch(void* const* d_in, const int* in_sizes, int n_in,
                              void* d_out, int out_size, void* d_ws, size_t ws_size,
                              hipStream_t stream) {
  const int* ei = (const int*)d_in[0];
  const float* x = (const float*)d_in[1];
  const float* ete = (const float*)d_in[2];
  const float* W = (const float*)d_in[3];
  const float* a = (const float*)d_in[4];
  float* out = (float*)d_out;

  float* ws = (float*)d_ws;
  float* xW1 = ws;                                  // N*128
  float* xW2 = xW1 + (size_t)NN * OF;               // N*128
  float* p1 = xW2 + (size_t)NN * OF;                // N
  float* p2 = p1 + NN;                              // N
  float* q3 = p2 + NN;                              // 64
  int* cnt = (int*)(q3 + NR);                       // N   } contiguous
  float* s = (float*)(cnt + NN);                    // N   } single memset
  float* ev = s + NN;                               // E
  float* g = ev + NE;                               // N*64
  int* roff = (int*)(g + (size_t)NN * NR);          // N+2 (pad keeps es 8B-aligned)
  int* cur = roff + NN + 2;                         // N
  int2* es = (int2*)(cur + NN);                     // E int2 (even word offset)
  float* wcsr = (float*)(es + NE);                  // E

  hipMemsetAsync(cnt, 0, 2 * NN * sizeof(int), stream);  // cnt + s
  k_q3<<<1, 64, 0, stream>>>(W, a, q3);
  k_node_pre<<<NN / 8, 128, 0, stream>>>(x, W, a, xW1, xW2, p1, p2);
  k_edge<<<NE / 16, 256, 0, stream>>>(ei, ete, q3, p1, p2, ev, s, cnt);
  k_scan<<<1, SCAN_T, 0, stream>>>(cnt, roff, cur);
  k_scatter<<<NE / 256, 256, 0, stream>>>(ei, ev, s, cur, es, wcsr);
  k_gather<<<NN / 4, 256, 0, stream>>>(es, wcsr, roff, ete, xW2, g, out);
  k_final<<<NN / 8, 128, 0, stream>>>(xW1, g, s, W, out);
}

// Round 4
// 440.400 us; speedup vs baseline: 8.4681x; 1.0189x over previous
//
#include <hip/hip_runtime.h>
#include <cmath>

#define NN 50000
#define NE 800000
#define INF_ 128
#define NR 64
#define OF 128
#define SCAN_T 1024

// q3[d] = sum_j W[(256+d),j] * a[j]
__global__ void k_q3(const float* __restrict__ W, const float* __restrict__ a,
                     float* __restrict__ q3) {
  int t = threadIdx.x;
  if (t < NR) {
    const float* row = W + (size_t)(2 * INF_ + t) * OF;
    float acc = 0.f;
    for (int j = 0; j < OF; ++j) acc = fmaf(row[j], a[j], acc);
    q3[t] = acc;
  }
}

// per-node precompute: xW1 = x@W1, xW2 = x@W2, p1 = xW1@a, p2 = xW2@a.
// Also zeroes cnt[] and s[] (contiguous 2*NN words at zbuf) — replaces the
// pathological 116us rocclr fillBuffer dispatch.
__global__ void k_node_pre(const float* __restrict__ x, const float* __restrict__ W,
                           const float* __restrict__ a,
                           float* __restrict__ xW1, float* __restrict__ xW2,
                           float* __restrict__ p1, float* __restrict__ p2,
                           int* __restrict__ zbuf) {
  int gid = blockIdx.x * 128 + threadIdx.x;
  if (gid < 2 * NN) zbuf[gid] = 0;
  __shared__ float xs[8][INF_];
  __shared__ float red[2][2][8];
  int nb = blockIdx.x * 8;
  int o = threadIdx.x;  // 0..127
  for (int t = 0; t < 8; ++t) xs[t][o] = x[(size_t)(nb + t) * INF_ + o];
  __syncthreads();
  float acc1[8] = {0.f, 0.f, 0.f, 0.f, 0.f, 0.f, 0.f, 0.f};
  float acc2[8] = {0.f, 0.f, 0.f, 0.f, 0.f, 0.f, 0.f, 0.f};
  for (int k = 0; k < INF_; ++k) {
    float w1 = W[(size_t)k * OF + o];
    float w2 = W[(size_t)(INF_ + k) * OF + o];
#pragma unroll
    for (int t = 0; t < 8; ++t) {
      acc1[t] = fmaf(xs[t][k], w1, acc1[t]);
      acc2[t] = fmaf(xs[t][k], w2, acc2[t]);
    }
  }
  float av = a[o];
  int wv = o >> 6, ln = o & 63;
#pragma unroll
  for (int t = 0; t < 8; ++t) {
    xW1[(size_t)(nb + t) * OF + o] = acc1[t];
    xW2[(size_t)(nb + t) * OF + o] = acc2[t];
    float v1 = acc1[t] * av, v2 = acc2[t] * av;
    for (int off = 32; off > 0; off >>= 1) {
      v1 += __shfl_down(v1, off, 64);
      v2 += __shfl_down(v2, off, 64);
    }
    if (ln == 0) { red[0][wv][t] = v1; red[1][wv][t] = v2; }
  }
  __syncthreads();
  if (o < 8) {
    p1[nb + o] = red[0][0][o] + red[0][1][o];
    p2[nb + o] = red[1][0][o] + red[1][1][o];
  }
}

// fused edge pass: ev[e] = exp(leaky_relu(p1[src]+p2[dst]+ete[e]·q3));
// s[src] += ev; cnt[src]++.   (no segment-max: |logit| << 88, exp is safe)
__global__ void k_edge(const int* __restrict__ ei, const float* __restrict__ ete,
                       const float* __restrict__ q3,
                       const float* __restrict__ p1, const float* __restrict__ p2,
                       float* __restrict__ ev, float* __restrict__ s,
                       int* __restrict__ cnt) {
  int l = threadIdx.x & 15;
  int e = blockIdx.x * 16 + (threadIdx.x >> 4);
  if (e >= NE) return;
  float4 t4 = ((const float4*)(ete + (size_t)e * NR))[l];
  float4 q4 = ((const float4*)q3)[l];
  float d = t4.x * q4.x + t4.y * q4.y + t4.z * q4.z + t4.w * q4.w;
  d += __shfl_xor(d, 8, 16);
  d += __shfl_xor(d, 4, 16);
  d += __shfl_xor(d, 2, 16);
  d += __shfl_xor(d, 1, 16);
  if (l == 0) {
    int src = ei[e], dst = ei[NE + e];
    float v = p1[src] + p2[dst] + d;
    v = v > 0.f ? v : 0.2f * v;
    float xv = __expf(v);
    ev[e] = xv;
    atomicAdd(s + src, xv);
    atomicAdd(cnt + src, 1);
  }
}

// single-block exclusive scan over cnt -> roff (+cur copy); roff[NN]=NE
__global__ void k_scan(const int* __restrict__ cnt, int* __restrict__ roff,
                       int* __restrict__ cur) {
  __shared__ int part[SCAN_T];
  int t = threadIdx.x;
  const int chunk = (NN + SCAN_T - 1) / SCAN_T;  // 49
  int beg = t * chunk;
  int end = beg + chunk < NN ? beg + chunk : NN;
  int sum = 0;
  for (int i = beg; i < end; ++i) sum += cnt[i];
  part[t] = sum;
  __syncthreads();
  for (int off = 1; off < SCAN_T; off <<= 1) {
    int v = (t >= off) ? part[t - off] : 0;
    __syncthreads();
    part[t] += v;
    __syncthreads();
  }
  int run = (t == 0) ? 0 : part[t - 1];
  for (int i = beg; i < end; ++i) {
    roff[i] = run;
    cur[i] = run;
    run += cnt[i];
  }
  if (t == SCAN_T - 1) roff[NN] = NE;
}

// scatter edges into CSR slots; w = ev/(s+eps) computed here (s is final)
__global__ void k_scatter(const int* __restrict__ ei, const float* __restrict__ ev,
                          const float* __restrict__ s, int* __restrict__ cur,
                          int2* __restrict__ es, float* __restrict__ wcsr) {
  int e = blockIdx.x * blockDim.x + threadIdx.x;
  if (e < NE) {
    int src = ei[e];
    int pos = atomicAdd(cur + src, 1);
    es[pos] = make_int2(e, ei[NE + e]);
    wcsr[pos] = ev[e] * (1.f / (s[src] + 1e-16f));
  }
}

// per-node gather: one wave per node. Metadata bulk-loaded coalesced, then
// broadcast via wave-uniform shfl; 8 edges of independent loads per step.
__global__ void k_gather(const int2* __restrict__ es, const float* __restrict__ wcsr,
                         const int* __restrict__ roff,
                         const float* __restrict__ ete, const float* __restrict__ xW2,
                         float* __restrict__ g, float* __restrict__ out) {
  int n = blockIdx.x * 4 + (threadIdx.x >> 6);
  int l = threadIdx.x & 63;
  if (n >= NN) return;
  int beg = roff[n], end = roff[n + 1];
  float gacc = 0.f, o0 = 0.f, o1 = 0.f;
  for (int jb = beg; jb < end; jb += 64) {
    int m = end - jb;
    if (m > 64) m = 64;
    int2 ed = make_int2(0, 0);
    float wv = 0.f;
    if (jb + l < end) { ed = es[jb + l]; wv = wcsr[jb + l]; }
    for (int jj = 0; jj < m; jj += 8) {
#pragma unroll
      for (int q = 0; q < 8; ++q) {
        // jj is a multiple of 8 and jj < m <= 64, so jj+q <= 63 always;
        // padded lanes carry w=0 and safe (0,0) indices.
        int e_q = __shfl(ed.x, jj + q, 64);
        int d_q = __shfl(ed.y, jj + q, 64);
        float w_q = __shfl(wv, jj + q, 64);
        float tv = ete[(size_t)e_q * NR + l];
        float2 xv = *(const float2*)(xW2 + (size_t)d_q * OF + 2 * l);
        gacc = fmaf(w_q, tv, gacc);
        o0 = fmaf(w_q, xv.x, o0);
        o1 = fmaf(w_q, xv.y, o1);
      }
    }
  }
  g[(size_t)n * NR + l] = gacc;
  *(float2*)(out + (size_t)n * OF + 2 * l) = make_float2(o0, o1);
}

// finalize: out = elu( (s/(s+1e-16))*xW1 + out + g@W3 ), 8 nodes/block
__global__ void k_final(const float* __restrict__ xW1, const float* __restrict__ g,
                        const float* __restrict__ s, const float* __restrict__ W,
                        float* __restrict__ out) {
  __shared__ float gs[8 * NR];
  int nb = blockIdx.x * 8;
  int o = threadIdx.x;  // 0..127
  for (int i = o; i < 8 * NR; i += 128) gs[i] = g[(size_t)nb * NR + i];
  __syncthreads();
  float acc[8] = {0.f, 0.f, 0.f, 0.f, 0.f, 0.f, 0.f, 0.f};
  for (int d = 0; d < NR; ++d) {
    float w3 = W[(size_t)(2 * INF_ + d) * OF + o];
#pragma unroll
    for (int t = 0; t < 8; ++t) acc[t] = fmaf(gs[t * NR + d], w3, acc[t]);
  }
#pragma unroll
  for (int t = 0; t < 8; ++t) {
    int n = nb + t;
    float sv = s[n];
    float sa = sv > 0.f ? sv / (sv + 1e-16f) : 0.f;
    float v = sa * xW1[(size_t)n * OF + o] + out[(size_t)n * OF + o] + acc[t];
    out[(size_t)n * OF + o] = v > 0.f ? v : expm1f(v);
  }
}

extern "C" void kernel_launch(void* const* d_in, const int* in_sizes, int n_in,
                              void* d_out, int out_size, void* d_ws, size_t ws_size,
                              hipStream_t stream) {
  const int* ei = (const int*)d_in[0];
  const float* x = (const float*)d_in[1];
  const float* ete = (const float*)d_in[2];
  const float* W = (const float*)d_in[3];
  const float* a = (const float*)d_in[4];
  float* out = (float*)d_out;

  float* ws = (float*)d_ws;
  float* xW1 = ws;                                  // N*128
  float* xW2 = xW1 + (size_t)NN * OF;               // N*128
  float* p1 = xW2 + (size_t)NN * OF;                // N
  float* p2 = p1 + NN;                              // N
  float* q3 = p2 + NN;                              // 64
  int* cnt = (int*)(q3 + NR);                       // N   } contiguous,
  float* s = (float*)(cnt + NN);                    // N   } zeroed in k_node_pre
  float* ev = s + NN;                               // E
  float* g = ev + NE;                               // N*64
  int* roff = (int*)(g + (size_t)NN * NR);          // N+2 (pad keeps es 8B-aligned)
  int* cur = roff + NN + 2;                         // N
  int2* es = (int2*)(cur + NN);                     // E int2 (even word offset)
  float* wcsr = (float*)(es + NE);                  // E

  k_q3<<<1, 64, 0, stream>>>(W, a, q3);
  k_node_pre<<<NN / 8, 128, 0, stream>>>(x, W, a, xW1, xW2, p1, p2, cnt);
  k_edge<<<NE / 16, 256, 0, stream>>>(ei, ete, q3, p1, p2, ev, s, cnt);
  k_scan<<<1, SCAN_T, 0, stream>>>(cnt, roff, cur);
  k_scatter<<<NE / 256, 256, 0, stream>>>(ei, ev, s, cur, es, wcsr);
  k_gather<<<NN / 4, 256, 0, stream>>>(es, wcsr, roff, ete, xW2, g, out);
  k_final<<<NN / 8, 128, 0, stream>>>(xW1, g, s, W, out);
}

// Round 5
// 373.923 us; speedup vs baseline: 9.9736x; 1.1778x over previous
//
#include <hip/hip_runtime.h>
#include <cmath>

#define NN 50000
#define NE 800000
#define INF_ 128
#define NR 64
#define OF 128
#define SCAN_T 1024

// zero cnt[]; block 0 also computes q3[d] = sum_j W[(256+d),j] * a[j]
__global__ void k_init(const float* __restrict__ W, const float* __restrict__ a,
                       float* __restrict__ q3, int* __restrict__ cnt) {
  int i = blockIdx.x * 256 + threadIdx.x;
  if (i < NN) cnt[i] = 0;
  if (blockIdx.x == 0 && threadIdx.x < NR) {
    const float* row = W + (size_t)(2 * INF_ + threadIdx.x) * OF;
    float acc = 0.f;
    for (int j = 0; j < OF; ++j) acc = fmaf(row[j], a[j], acc);
    q3[threadIdx.x] = acc;
  }
}

// per-node precompute: xW1 = x@W1, xW2 = x@W2, p1 = xW1@a, p2 = xW2@a.
// Fused: src-degree histogram (grid*block == NE exactly, one edge per thread).
__global__ void k_node_pre(const float* __restrict__ x, const float* __restrict__ W,
                           const float* __restrict__ a, const int* __restrict__ ei,
                           float* __restrict__ xW1, float* __restrict__ xW2,
                           float* __restrict__ p1, float* __restrict__ p2,
                           int* __restrict__ cnt) {
  int gid = blockIdx.x * 128 + threadIdx.x;  // 0..799999 == edge id
  atomicAdd(cnt + ei[gid], 1);
  __shared__ float xs[8][INF_];
  __shared__ float red[2][2][8];
  int nb = blockIdx.x * 8;
  int o = threadIdx.x;  // 0..127
  for (int t = 0; t < 8; ++t) xs[t][o] = x[(size_t)(nb + t) * INF_ + o];
  __syncthreads();
  float acc1[8] = {0.f, 0.f, 0.f, 0.f, 0.f, 0.f, 0.f, 0.f};
  float acc2[8] = {0.f, 0.f, 0.f, 0.f, 0.f, 0.f, 0.f, 0.f};
  for (int k = 0; k < INF_; ++k) {
    float w1 = W[(size_t)k * OF + o];
    float w2 = W[(size_t)(INF_ + k) * OF + o];
#pragma unroll
    for (int t = 0; t < 8; ++t) {
      acc1[t] = fmaf(xs[t][k], w1, acc1[t]);
      acc2[t] = fmaf(xs[t][k], w2, acc2[t]);
    }
  }
  float av = a[o];
  int wv = o >> 6, ln = o & 63;
#pragma unroll
  for (int t = 0; t < 8; ++t) {
    xW1[(size_t)(nb + t) * OF + o] = acc1[t];
    xW2[(size_t)(nb + t) * OF + o] = acc2[t];
    float v1 = acc1[t] * av, v2 = acc2[t] * av;
    for (int off = 32; off > 0; off >>= 1) {
      v1 += __shfl_down(v1, off, 64);
      v2 += __shfl_down(v2, off, 64);
    }
    if (ln == 0) { red[0][wv][t] = v1; red[1][wv][t] = v2; }
  }
  __syncthreads();
  if (o < 8) {
    p1[nb + o] = red[0][0][o] + red[0][1][o];
    p2[nb + o] = red[1][0][o] + red[1][1][o];
  }
}

// single-block exclusive scan over cnt -> roff (+cur copy); roff[NN]=NE
__global__ void k_scan(const int* __restrict__ cnt, int* __restrict__ roff,
                       int* __restrict__ cur) {
  __shared__ int part[SCAN_T];
  int t = threadIdx.x;
  const int chunk = (NN + SCAN_T - 1) / SCAN_T;  // 49
  int beg = t * chunk;
  int end = beg + chunk < NN ? beg + chunk : NN;
  int sum = 0;
  for (int i = beg; i < end; ++i) sum += cnt[i];
  part[t] = sum;
  __syncthreads();
  for (int off = 1; off < SCAN_T; off <<= 1) {
    int v = (t >= off) ? part[t - off] : 0;
    __syncthreads();
    part[t] += v;
    __syncthreads();
  }
  int run = (t == 0) ? 0 : part[t - 1];
  for (int i = beg; i < end; ++i) {
    roff[i] = run;
    cur[i] = run;
    run += cnt[i];
  }
  if (t == SCAN_T - 1) roff[NN] = NE;
}

// scatter edge ids + dst into CSR slots (index-only; no weights needed)
__global__ void k_scatter(const int* __restrict__ ei, int* __restrict__ cur,
                          int2* __restrict__ es) {
  int e = blockIdx.x * blockDim.x + threadIdx.x;
  if (e < NE) {
    int pos = atomicAdd(cur + ei[e], 1);
    es[pos] = make_int2(e, ei[NE + e]);
  }
}

// fully fused per-node pass: one wave per node, single read of ete.
// For each edge: logit = p1[n] + p2[dst] + ete[e]·q3 (64-lane butterfly),
// ev = exp(leaky_relu(logit));  accumulate ssum, ev*ete, ev*xW2[dst]
// unnormalized; scale by 1/(ssum+eps) at the end (softmax denom is uniform
// per node, so normalization commutes with the sums). Padded lanes carry
// p2 = -inf so ev = 0 (branch-free masking).
__global__ void k_gather(const int2* __restrict__ es, const int* __restrict__ roff,
                         const float* __restrict__ ete, const float* __restrict__ xW2,
                         const float* __restrict__ q3, const float* __restrict__ p1,
                         const float* __restrict__ p2,
                         float* __restrict__ g, float* __restrict__ out,
                         float* __restrict__ s) {
  int n = blockIdx.x * 4 + (threadIdx.x >> 6);
  int l = threadIdx.x & 63;
  if (n >= NN) return;
  int beg = roff[n], end = roff[n + 1];
  float q3l = q3[l];
  float p1n = p1[n];
  float ssum = 0.f, gacc = 0.f, o0 = 0.f, o1 = 0.f;
  for (int jb = beg; jb < end; jb += 64) {
    int m = end - jb;
    if (m > 64) m = 64;
    int2 ed = make_int2(0, 0);
    float pv = -INFINITY;  // padded lanes -> ev = exp(-inf) = 0
    if (jb + l < end) { ed = es[jb + l]; pv = p2[ed.y]; }
    for (int jj = 0; jj < m; jj += 8) {
#pragma unroll
      for (int q = 0; q < 8; ++q) {
        // jj+q <= 63 always; overshoot lanes have pv=-inf and safe (0,0) idx
        int e_q = __shfl(ed.x, jj + q, 64);
        int d_q = __shfl(ed.y, jj + q, 64);
        float p2q = __shfl(pv, jj + q, 64);
        float tv = ete[(size_t)e_q * NR + l];
        float2 xv = *(const float2*)(xW2 + (size_t)d_q * OF + 2 * l);
        float ds = tv * q3l;
        ds += __shfl_xor(ds, 1, 64);
        ds += __shfl_xor(ds, 2, 64);
        ds += __shfl_xor(ds, 4, 64);
        ds += __shfl_xor(ds, 8, 64);
        ds += __shfl_xor(ds, 16, 64);
        ds += __shfl_xor(ds, 32, 64);
        float v = p1n + p2q + ds;
        v = v > 0.f ? v : 0.2f * v;
        float evq = __expf(v);
        ssum += evq;
        gacc = fmaf(evq, tv, gacc);
        o0 = fmaf(evq, xv.x, o0);
        o1 = fmaf(evq, xv.y, o1);
      }
    }
  }
  float inv = 1.f / (ssum + 1e-16f);
  g[(size_t)n * NR + l] = gacc * inv;
  *(float2*)(out + (size_t)n * OF + 2 * l) = make_float2(o0 * inv, o1 * inv);
  if (l == 0) s[n] = ssum;
}

// finalize: out = elu( (s/(s+1e-16))*xW1 + out + g@W3 ), 8 nodes/block
__global__ void k_final(const float* __restrict__ xW1, const float* __restrict__ g,
                        const float* __restrict__ s, const float* __restrict__ W,
                        float* __restrict__ out) {
  __shared__ float gs[8 * NR];
  int nb = blockIdx.x * 8;
  int o = threadIdx.x;  // 0..127
  for (int i = o; i < 8 * NR; i += 128) gs[i] = g[(size_t)nb * NR + i];
  __syncthreads();
  float acc[8] = {0.f, 0.f, 0.f, 0.f, 0.f, 0.f, 0.f, 0.f};
  for (int d = 0; d < NR; ++d) {
    float w3 = W[(size_t)(2 * INF_ + d) * OF + o];
#pragma unroll
    for (int t = 0; t < 8; ++t) acc[t] = fmaf(gs[t * NR + d], w3, acc[t]);
  }
#pragma unroll
  for (int t = 0; t < 8; ++t) {
    int n = nb + t;
    float sv = s[n];
    float sa = sv > 0.f ? sv / (sv + 1e-16f) : 0.f;
    float v = sa * xW1[(size_t)n * OF + o] + out[(size_t)n * OF + o] + acc[t];
    out[(size_t)n * OF + o] = v > 0.f ? v : expm1f(v);
  }
}

extern "C" void kernel_launch(void* const* d_in, const int* in_sizes, int n_in,
                              void* d_out, int out_size, void* d_ws, size_t ws_size,
                              hipStream_t stream) {
  const int* ei = (const int*)d_in[0];
  const float* x = (const float*)d_in[1];
  const float* ete = (const float*)d_in[2];
  const float* W = (const float*)d_in[3];
  const float* a = (const float*)d_in[4];
  float* out = (float*)d_out;

  float* ws = (float*)d_ws;
  float* xW1 = ws;                                  // N*128  (6.4M words)
  float* xW2 = xW1 + (size_t)NN * OF;               // N*128  (6.4M)
  float* g = xW2 + (size_t)NN * OF;                 // N*64   (3.2M) -> even offset
  int2* es = (int2*)(g + (size_t)NN * NR);          // E int2 (8B-aligned: even word offset)
  float* p1 = (float*)(es + NE);                    // N
  float* p2 = p1 + NN;                              // N
  float* q3 = p2 + NN;                              // 64
  int* cnt = (int*)(q3 + NR);                       // N
  float* s = (float*)(cnt + NN);                    // N
  int* roff = (int*)(s + NN);                       // N+1
  int* cur = roff + NN + 1;                         // N
  // total ~18.0M words = 72 MB

  k_init<<<(NN + 255) / 256, 256, 0, stream>>>(W, a, q3, cnt);
  k_node_pre<<<NN / 8, 128, 0, stream>>>(x, W, a, ei, xW1, xW2, p1, p2, cnt);
  k_scan<<<1, SCAN_T, 0, stream>>>(cnt, roff, cur);
  k_scatter<<<NE / 256, 256, 0, stream>>>(ei, cur, es);
  k_gather<<<NN / 4, 256, 0, stream>>>(es, roff, ete, xW2, q3, p1, p2, g, out, s);
  k_final<<<NN / 8, 128, 0, stream>>>(xW1, g, s, W, out);
}